// Round 8
// baseline (147.699 us; speedup 1.0000x reference)
//
#include <hip/hip_runtime.h>
#include <hip/hip_bf16.h>
#include <stdint.h>

typedef __attribute__((ext_vector_type(8))) short bf16x8;
typedef __attribute__((ext_vector_type(4))) float f32x4;

#define DEVI static __device__ __forceinline__

// Problem sizes (fixed)
static constexpr int B_SZ = 4096, N_SZ = 128, H_SZ = 128, W_SZ = 64;

// ws layout (bytes), all 16B aligned
static constexpr size_t OFF_W1 = 0;                      // 128 * 128*128 bf16 = 4 MB (UNswizzled [n][c][h])
static constexpr size_t OFF_W2 = OFF_W1 + 4194304;       // 128 * 64*128 bf16 = 2 MB (UNswizzled [n][w][k])
static constexpr size_t OFF_F1 = OFF_W2 + 2097152;       // 128*128 bf16 = 32 KB (swizzled [o][h])
static constexpr size_t OFF_F2 = OFF_F1 + 32768;         // 384*128 bf16 = 96 KB (swizzled [o][j])
static constexpr size_t OFF_H  = OFF_F2 + 98304;         // 4096*128 bf16 = 1 MB (per-128-row tile, swizzled)

typedef const __attribute__((address_space(1))) void gvoid;
typedef __attribute__((address_space(3))) void lvoid;

DEVI unsigned short f2bf(float f) {
  union { __hip_bfloat16 b; unsigned short u; } cv;
  cv.b = __float2bfloat16(f);
  return cv.u;
}
DEVI float bf2f(unsigned short u) {
  union { unsigned int i; float f; } cv;
  cv.i = ((unsigned int)u) << 16;
  return cv.f;
}

// Raw workgroup barrier: execution sync + LDS visibility (lgkmcnt), but does NOT
// drain vmcnt -> global_load_lds prefetches stay in flight across it.
DEVI void bar_lds() {
  __builtin_amdgcn_sched_barrier(0);
  asm volatile("s_waitcnt lgkmcnt(0)" ::: "memory");
  __builtin_amdgcn_s_barrier();
  __builtin_amdgcn_sched_barrier(0);
}

// Read one MFMA fragment (8 contiguous bf16 along k) from a swizzled bf16 LDS tile.
// Tile layout: row stride 256B; 16B slot s stored at (s ^ (row&7)).
DEVI bf16x8 frag_ld(const unsigned char* base, int row, int kslot) {
  return *reinterpret_cast<const bf16x8*>(base + row * 256 + (((kslot ^ (row & 7)) << 4)));
}
// Unswizzled fragment read (global memory, 256B rows).
DEVI bf16x8 gfrag_ld(const unsigned char* base, int row, int kslot) {
  return *reinterpret_cast<const bf16x8*>(base + row * 256 + (kslot << 4));
}

// Stage an nrows x 128 fp32 tile (row stride in elems) into swizzled bf16 LDS (f1 only).
DEVI void stage_f32_tile(const float* src, int row_stride, unsigned char* dst, int tid, int nrows) {
  for (int t = tid; t < nrows * 16; t += 256) {
    int row = t >> 4, s = t & 15;
    const float* p = src + (size_t)row * row_stride + s * 8;
    union { unsigned short u[8]; uint4 v; } pk;
#pragma unroll
    for (int j = 0; j < 8; ++j) pk.u[j] = f2bf(p[j]);
    *reinterpret_cast<uint4*>(dst + row * 256 + ((s ^ (row & 7)) << 4)) = pk.v;
  }
}

// Async-stage one 64x128 fp32 SE tile into LDS (linear rows of 512B) via
// global_load_lds width=16. Source granules pre-swizzled per lane with the even
// XOR (g ^ ((row&7)<<1)) so swizzled fragment reads are low-conflict (rule #21:
// same involution on source permutation and read).
DEVI void stage_async(const float* se, int brow0, int n, unsigned char* dstbase,
                      int wave, int lane) {
  const int rr = lane >> 5;   // row parity within each 1KB call
  const int g  = lane & 31;   // LDS granule position this lane fills
#pragma unroll
  for (int c = 0; c < 8; ++c) {
    const int rl = wave * 16 + c * 2 + rr;        // local row 0..63
    const int gsrc = g ^ ((rl & 7) << 1);         // source granule (even swizzle)
    const float* gp = se + ((size_t)(brow0 + rl) * 128 + n) * 128 + gsrc * 4;
    unsigned char* lp = dstbase + (wave * 16 + c * 2) * 512;  // wave-uniform; HW adds lane*16
    __builtin_amdgcn_global_load_lds((gvoid*)gp, (lvoid*)lp, 16, 0, 0);
  }
}

// ---------------- prep: convert+transpose weights into ws (bf16) + logits copy ----------------
__global__ __launch_bounds__(256) void prep_kernel(const float* __restrict__ rw1,
                                                   const float* __restrict__ rw2,
                                                   const float* __restrict__ fc1w,
                                                   const float* __restrict__ fc2w,
                                                   const float* __restrict__ slog,
                                                   float* __restrict__ out,
                                                   unsigned char* __restrict__ ws) {
  const int T_W1 = 128 * 128 * 16;  // (n,s,c): W1t[n][c][h=s*8+j] = rw1[n][h][c]
  const int T_W2 = 128 * 64 * 16;   // (n,s,w): W2t[n][w][k=s*8+j] = rw2[n][k][w]
  const int T_F1 = 128 * 16;        // (o,s):   F1s[o][h] = fc1w[o][h]  (swizzled)
  const int T_F2 = 384 * 16;
  const int T_LG = 131072;          // logits: 2MB as uint4 granules
  int id = blockIdx.x * 256 + threadIdx.x;
  if (id < T_W1) {
    int c = id & 127, rest = id >> 7;
    int s = rest & 15, n = rest >> 4;
    const float* src = rw1 + (size_t)n * 16384 + (size_t)(s * 8) * 128 + c;
    union { unsigned short u[8]; uint4 v; } pk;
#pragma unroll
    for (int j = 0; j < 8; ++j) pk.u[j] = f2bf(src[(size_t)j * 128]);
    size_t dst = OFF_W1 + ((size_t)n * 128 + c) * 256 + (size_t)(s << 4);
    *reinterpret_cast<uint4*>(ws + dst) = pk.v;
    return;
  }
  id -= T_W1;
  if (id < T_W2) {
    int w = id & 63, rest = id >> 6;
    int s = rest & 15, n = rest >> 4;
    const float* src = rw2 + (size_t)n * 8192 + (size_t)(s * 8) * 64 + w;
    union { unsigned short u[8]; uint4 v; } pk;
#pragma unroll
    for (int j = 0; j < 8; ++j) pk.u[j] = f2bf(src[(size_t)j * 64]);
    size_t dst = OFF_W2 + ((size_t)n * 64 + w) * 256 + (size_t)(s << 4);
    *reinterpret_cast<uint4*>(ws + dst) = pk.v;
    return;
  }
  id -= T_W2;
  if (id < T_F1) {
    int s = id & 15, o = id >> 4;
    const float* src = fc1w + (size_t)o * 128 + s * 8;
    union { unsigned short u[8]; uint4 v; } pk;
#pragma unroll
    for (int j = 0; j < 8; ++j) pk.u[j] = f2bf(src[j]);
    *reinterpret_cast<uint4*>(ws + OFF_F1 + (size_t)o * 256 + ((s ^ (o & 7)) << 4)) = pk.v;
    return;
  }
  id -= T_F1;
  if (id < T_F2) {
    int s = id & 15, o = id >> 4;
    const float* src = fc2w + (size_t)o * 128 + s * 8;
    union { unsigned short u[8]; uint4 v; } pk;
#pragma unroll
    for (int j = 0; j < 8; ++j) pk.u[j] = f2bf(src[j]);
    *reinterpret_cast<uint4*>(ws + OFF_F2 + (size_t)o * 256 + ((s ^ (o & 7)) << 4)) = pk.v;
    return;
  }
  id -= T_F2;
  if (id < T_LG) {
    reinterpret_cast<uint4*>(out)[id] = reinterpret_cast<const uint4*>(slog)[id];
  }
}

// ---------------- recon v8: async gload_lds fp32 SE staging, counted vmcnt ----------------
// Block = (node n, 512 b-rows as 8x64 subtiles). W1+W2 frags in VGPR (loaded once).
// SE staged as RAW FP32 via global_load_lds (8 insts/wave/tile), double-buffered;
// f32->bf16 conversion happens at fragment assembly in G1 (no staging VALU at all).
// Per iter: [vmcnt(N)+bar] G1(bufc) | [C] | issue gload(t+2->bufc), epi1->sHN | [F] | G2, epi2.
// vmcnt N derivation (issue order: ... g(t+1)x8, st(t-1)x4, g(t+2)x8, st(t)x4):
//   t=0: 8 (only g(1) newer)   t=1: 12 (g(2)+st(0))   t=2..6: 16   t=7: 8 (st(5)+st(6)).
// tmp output: bf16 [b][n][w] stashed in the upper half of each b's 32KB out3 slot.
__global__ __launch_bounds__(256, 2) void recon_kernel(const float* __restrict__ se,
                                                       const float* __restrict__ rb1,
                                                       const float* __restrict__ rb2,
                                                       const unsigned char* __restrict__ ws,
                                                       float* __restrict__ out3) {
  __shared__ unsigned char sSE[2][32768];  // SE 64-row fp32 tiles (linear 512B rows, src-swizzled)
  __shared__ unsigned char sHN[16384];     // hn 64-row bf16 tile (swizzled rows b, 256B)

  const int tid = threadIdx.x;
  const int n = blockIdx.x;    // 0..127 node (linear id % 8 == n % 8 -> same-n blocks share XCD)
  const int btg = blockIdx.y;  // 0..7  -> 512 b-rows each
  const int b0 = btg * 512;

  const int wave = tid >> 6, lane = tid & 63;
  const int wm = wave >> 1, wq = wave & 1;  // wm: out-row half, wq: b half (32 each)
  const int lr = lane & 15, lk = lane >> 4;

  // A-fragments of W1 (64 rows this wave-half) and W2 (32 rows): loop-invariant -> VGPRs.
  const unsigned char* w1b = ws + OFF_W1 + (size_t)n * 32768;
  const unsigned char* w2b = ws + OFF_W2 + (size_t)n * 16384;
  bf16x8 w1f[4][4], w2f[2][4];
#pragma unroll
  for (int m = 0; m < 4; ++m)
#pragma unroll
    for (int kk = 0; kk < 4; ++kk)
      w1f[m][kk] = gfrag_ld(w1b, wm * 64 + m * 16 + lr, kk * 4 + lk);
#pragma unroll
  for (int m = 0; m < 2; ++m)
#pragma unroll
    for (int kk = 0; kk < 4; ++kk)
      w2f[m][kk] = gfrag_ld(w2b, wm * 32 + m * 16 + lr, kk * 4 + lk);

  // biases (constant per lane across all tiles)
  float bias1[4][4], bias2[2][4];
#pragma unroll
  for (int m = 0; m < 4; ++m)
#pragma unroll
    for (int j = 0; j < 4; ++j) bias1[m][j] = rb1[(size_t)n * 128 + wm * 64 + m * 16 + lk * 4 + j];
#pragma unroll
  for (int m = 0; m < 2; ++m)
#pragma unroll
    for (int j = 0; j < 4; ++j) bias2[m][j] = rb2[(size_t)n * 64 + wm * 32 + m * 16 + lk * 4 + j];

  unsigned short* outus = reinterpret_cast<unsigned short*>(out3);

  // prologue: async-stage tiles 0 and 1
  stage_async(se, b0, n, sSE[0], wave, lane);
  stage_async(se, b0 + 64, n, sSE[1], wave, lane);

#pragma unroll 1
  for (int t = 0; t < 8; ++t) {
    unsigned char* bufc = sSE[t & 1];

    // tile-t ready gate: counted vmcnt (never drains the younger prefetch), then barrier
    __builtin_amdgcn_sched_barrier(0);
    if (t == 0 || t == 7) asm volatile("s_waitcnt vmcnt(8)" ::: "memory");
    else if (t == 1)      asm volatile("s_waitcnt vmcnt(12)" ::: "memory");
    else                  asm volatile("s_waitcnt vmcnt(16)" ::: "memory");
    __builtin_amdgcn_s_barrier();
    __builtin_amdgcn_sched_barrier(0);

    // GEMM1': 128(h_out) x 64(b) x 128(k); wave owns 64 x 32.
    // B-fragments: 32B fp32 from bufc (granule pair (2s)^((b&7)<<1)), cvt to bf16.
    f32x4 acc[4][2] = {};
#pragma unroll
    for (int kk = 0; kk < 4; ++kk) {
      const int slot = kk * 4 + lk;
      bf16x8 bv[2];
#pragma unroll
      for (int q = 0; q < 2; ++q) {
        const int b = wq * 32 + q * 16 + lr;
        const unsigned char* base = bufc + b * 512 + (((2 * slot) ^ ((b & 7) << 1)) << 4);
        float4 lo = *reinterpret_cast<const float4*>(base);
        float4 hi = *reinterpret_cast<const float4*>(base + 16);
        union { unsigned short u[8]; bf16x8 v; } pk;
        pk.u[0] = f2bf(lo.x); pk.u[1] = f2bf(lo.y); pk.u[2] = f2bf(lo.z); pk.u[3] = f2bf(lo.w);
        pk.u[4] = f2bf(hi.x); pk.u[5] = f2bf(hi.y); pk.u[6] = f2bf(hi.z); pk.u[7] = f2bf(hi.w);
        bv[q] = pk.v;
      }
#pragma unroll
      for (int m = 0; m < 4; ++m)
#pragma unroll
        for (int q = 0; q < 2; ++q)
          acc[m][q] = __builtin_amdgcn_mfma_f32_16x16x32_bf16(w1f[m][kk], bv[q], acc[m][q], 0, 0, 0);
    }
    bar_lds();  // [C] all waves' G1 reads of bufc done; prev G2's sHN reads done

    // issue async stage of tile t+2 into bufc (readers just drained at [C]);
    // consumed at iter t+2 top -> ~2 iters of latency cover, never drained early.
    if (t < 6) stage_async(se, b0 + (t + 2) * 64, n, bufc, wave, lane);

    // epilogue1: hn[b][k] = relu(C1t[k][b] + rb1[k]) -> bf16 into sHN
    // lane: b = wq*32+q*16+lr, k = wm*64+m*16+lk*4+j  -> 8B write
#pragma unroll
    for (int m = 0; m < 4; ++m) {
      const int k0 = wm * 64 + m * 16 + lk * 4;
      const int s16 = k0 >> 3, half = (k0 >> 2) & 1;
#pragma unroll
      for (int q = 0; q < 2; ++q) {
        const int b = wq * 32 + q * 16 + lr;
        union { unsigned short u[4]; uint2 v; } pk;
#pragma unroll
        for (int j = 0; j < 4; ++j) {
          float v = acc[m][q][j] + bias1[m][j];
          v = v > 0.f ? v : 0.f;
          pk.u[j] = f2bf(v);
        }
        *reinterpret_cast<uint2*>(sHN + b * 256 + ((s16 ^ (b & 7)) << 4) + half * 8) = pk.v;
      }
    }
    bar_lds();  // [F] sHN ready

    // GEMM2': 64(w) x 64(b) x 128(k); wave owns 32 x 32
    f32x4 acc2[2][2] = {};
#pragma unroll
    for (int kk = 0; kk < 4; ++kk) {
      const int slot = kk * 4 + lk;
      bf16x8 bv[2];
#pragma unroll
      for (int q = 0; q < 2; ++q) bv[q] = frag_ld(sHN, wq * 32 + q * 16 + lr, slot);
#pragma unroll
      for (int m = 0; m < 2; ++m)
#pragma unroll
        for (int q = 0; q < 2; ++q)
          acc2[m][q] = __builtin_amdgcn_mfma_f32_16x16x32_bf16(w2f[m][kk], bv[q], acc2[m][q], 0, 0, 0);
    }

    // epilogue2: tmp[b][n][w] bf16 at float-offset 4096 of b's out3 slot (4 stores)
    const int bt0 = b0 + t * 64;
#pragma unroll
    for (int m = 0; m < 2; ++m) {
      const int w0 = wm * 32 + m * 16 + lk * 4;
#pragma unroll
      for (int q = 0; q < 2; ++q) {
        const int b = bt0 + wq * 32 + q * 16 + lr;
        union { unsigned short u[4]; uint2 v; } pk;
#pragma unroll
        for (int j = 0; j < 4; ++j) pk.u[j] = f2bf(acc2[m][q][j] + bias2[m][j]);
        *reinterpret_cast<uint2*>(outus + (size_t)b * 16384 + 8192 + n * 64 + w0) = pk.v;
      }
    }
    // no closing barrier: G2(t) r:sHN vs epi1(t+1) w:sHN separated by [C](t+1).
  }
}

// ---------------- transpose: tmp bf16 [b][n][w] -> out3 fp32 [b][w][n], LDS-free ----------------
__global__ __launch_bounds__(256) void transpose_kernel(float* __restrict__ out3) {
  const int b = blockIdx.x, wave = threadIdx.x >> 6, lane = threadIdx.x & 63;
  const unsigned short* t = reinterpret_cast<const unsigned short*>(out3) + (size_t)b * 16384 + 8192;
  float* dst = out3 + (size_t)b * 8192;
  uint4 r[2][2];
#pragma unroll
  for (int half = 0; half < 2; ++half) {
    const int g = half * 4 + wave;
    r[half][0] = *reinterpret_cast<const uint4*>(t + lane * 64 + g * 8);
    r[half][1] = *reinterpret_cast<const uint4*>(t + (size_t)(lane + 64) * 64 + g * 8);
  }
  __syncthreads();  // all reads done before dst writes clobber the tmp region
#pragma unroll
  for (int half = 0; half < 2; ++half) {
    const int g = half * 4 + wave;
    union { uint4 v; unsigned short u[8]; } p0, p1;
    p0.v = r[half][0];
    p1.v = r[half][1];
#pragma unroll
    for (int j = 0; j < 8; ++j) {
      dst[(g * 8 + j) * 128 + lane] = bf2f(p0.u[j]);
      dst[(g * 8 + j) * 128 + lane + 64] = bf2f(p1.u[j]);
    }
  }
}

// ---------------- forecast stage 1: h = relu(emb @ fc1^T + b1) -> ws (bf16, tile-swizzled) ----------------
__global__ __launch_bounds__(256) void f1_kernel(const float* __restrict__ emb,
                                                 const float* __restrict__ fc1b,
                                                 const unsigned char* __restrict__ ws,
                                                 unsigned char* __restrict__ hsw) {
  __shared__ unsigned char sA[32768];
  __shared__ unsigned char sB[32768];
  const int tid = threadIdx.x;
  const int bt = blockIdx.x;
  const int b0 = bt * 128;
  {
    const uint4* wp = reinterpret_cast<const uint4*>(ws + OFF_F1);
    uint4* d = reinterpret_cast<uint4*>(sB);
    for (int c = tid; c < 2048; c += 256) d[c] = wp[c];
  }
  stage_f32_tile(emb + (size_t)b0 * 128, 128, sA, tid, 128);
  __syncthreads();

  const int wave = tid >> 6, lane = tid & 63;
  const int wm = wave >> 1, wn = wave & 1;
  const int lr = lane & 15, lk = lane >> 4;

  f32x4 acc[4][4] = {};
#pragma unroll
  for (int kk = 0; kk < 4; ++kk) {
    bf16x8 af[4], bfv[4];
#pragma unroll
    for (int m = 0; m < 4; ++m) af[m] = frag_ld(sA, wm * 64 + m * 16 + lr, kk * 4 + lk);
#pragma unroll
    for (int q = 0; q < 4; ++q) bfv[q] = frag_ld(sB, wn * 64 + q * 16 + lr, kk * 4 + lk);
#pragma unroll
    for (int m = 0; m < 4; ++m)
#pragma unroll
      for (int q = 0; q < 4; ++q)
        acc[m][q] = __builtin_amdgcn_mfma_f32_16x16x32_bf16(af[m], bfv[q], acc[m][q], 0, 0, 0);
  }

  unsigned char* tile = hsw + (size_t)bt * 32768;
#pragma unroll
  for (int q = 0; q < 4; ++q) {
    int c = wn * 64 + q * 16 + lr;
    float bias = fc1b[c];
#pragma unroll
    for (int m = 0; m < 4; ++m) {
#pragma unroll
      for (int j = 0; j < 4; ++j) {
        int r = wm * 64 + m * 16 + lk * 4 + j;
        float v = acc[m][q][j] + bias;
        v = v > 0.f ? v : 0.f;
        *reinterpret_cast<unsigned short*>(tile + r * 256 + ((c * 2) ^ ((r & 7) << 4))) = f2bf(v);
      }
    }
  }
}

// ---------------- forecast stage 2: forecast = h @ fc2^T + b2 ----------------
__global__ __launch_bounds__(256) void f2_kernel(const unsigned char* __restrict__ hsw,
                                                 const unsigned char* __restrict__ f2s,
                                                 const float* __restrict__ fc2b,
                                                 float* __restrict__ out2) {
  __shared__ unsigned char sA[32768];
  __shared__ unsigned char sB[32768];
  const int tid = threadIdx.x;
  const int bt = blockIdx.x;      // 0..31
  const int ch = blockIdx.y;      // 0..2 (chunks of 128 output cols)
  const int b0 = bt * 128;
  {
    const uint4* ap = reinterpret_cast<const uint4*>(hsw + (size_t)bt * 32768);
    uint4* da = reinterpret_cast<uint4*>(sA);
    for (int c = tid; c < 2048; c += 256) da[c] = ap[c];
    const uint4* bp = reinterpret_cast<const uint4*>(f2s + (size_t)ch * 32768);
    uint4* db = reinterpret_cast<uint4*>(sB);
    for (int c = tid; c < 2048; c += 256) db[c] = bp[c];
  }
  __syncthreads();

  const int wave = tid >> 6, lane = tid & 63;
  const int wm = wave >> 1, wn = wave & 1;
  const int lr = lane & 15, lk = lane >> 4;

  f32x4 acc[4][4] = {};
#pragma unroll
  for (int kk = 0; kk < 4; ++kk) {
    bf16x8 af[4], bfv[4];
#pragma unroll
    for (int m = 0; m < 4; ++m) af[m] = frag_ld(sA, wm * 64 + m * 16 + lr, kk * 4 + lk);
#pragma unroll
    for (int q = 0; q < 4; ++q) bfv[q] = frag_ld(sB, wn * 64 + q * 16 + lr, kk * 4 + lk);
#pragma unroll
    for (int m = 0; m < 4; ++m)
#pragma unroll
      for (int q = 0; q < 4; ++q)
        acc[m][q] = __builtin_amdgcn_mfma_f32_16x16x32_bf16(af[m], bfv[q], acc[m][q], 0, 0, 0);
  }

#pragma unroll
  for (int q = 0; q < 4; ++q) {
    int o = ch * 128 + wn * 64 + q * 16 + lr;
    float bias = fc2b[o];
#pragma unroll
    for (int m = 0; m < 4; ++m) {
#pragma unroll
      for (int j = 0; j < 4; ++j) {
        int r = wm * 64 + m * 16 + lk * 4 + j;
        out2[(size_t)(b0 + r) * 384 + o] = acc[m][q][j] + bias;
      }
    }
  }
}

extern "C" void kernel_launch(void* const* d_in, const int* in_sizes, int n_in,
                              void* d_out, int out_size, void* d_ws, size_t ws_size,
                              hipStream_t stream) {
  const float* emb  = (const float*)d_in[0];
  const float* se   = (const float*)d_in[1];
  const float* slog = (const float*)d_in[2];
  const float* fc1w = (const float*)d_in[3];
  const float* fc1b = (const float*)d_in[4];
  const float* fc2w = (const float*)d_in[5];
  const float* fc2b = (const float*)d_in[6];
  const float* rw1  = (const float*)d_in[7];
  const float* rb1  = (const float*)d_in[8];
  const float* rw2  = (const float*)d_in[9];
  const float* rb2  = (const float*)d_in[10];
  float* out = (float*)d_out;
  unsigned char* ws = (unsigned char*)d_ws;

  // weight prep (bf16 convert + transpose into ws) + logits passthrough copy
  prep_kernel<<<2080, 256, 0, stream>>>(rw1, rw2, fc1w, fc2w, slog, out, ws);

  // forecast head
  f1_kernel<<<32, 256, 0, stream>>>(emb, fc1b, ws, ws + OFF_H);
  f2_kernel<<<dim3(32, 3), 256, 0, stream>>>(ws + OFF_H, ws + OFF_F2, fc2b,
                                             out + (size_t)B_SZ * N_SZ);

  // reconstruction heads (dominant): async gload_lds recon -> bf16 tmp -> transpose
  float* out3 = out + (size_t)B_SZ * N_SZ + (size_t)B_SZ * 384;
  recon_kernel<<<dim3(128, 8), 256, 0, stream>>>(se, rb1, rb2, ws, out3);
  transpose_kernel<<<4096, 256, 0, stream>>>(out3);
}

// Round 9
// 136.217 us; speedup vs baseline: 1.0843x; 1.0843x over previous
//
#include <hip/hip_runtime.h>
#include <hip/hip_bf16.h>
#include <stdint.h>

typedef __attribute__((ext_vector_type(8))) short bf16x8;
typedef __attribute__((ext_vector_type(4))) float f32x4;

#define DEVI static __device__ __forceinline__

// Problem sizes (fixed)
static constexpr int B_SZ = 4096, N_SZ = 128, H_SZ = 128, W_SZ = 64;

// ws layout (bytes), all 16B aligned
static constexpr size_t OFF_W1 = 0;                      // 128 * 128*128 bf16 = 4 MB (UNswizzled [n][c][h])
static constexpr size_t OFF_W2 = OFF_W1 + 4194304;       // 128 * 64*128 bf16 = 2 MB (UNswizzled [n][w][k])
static constexpr size_t OFF_F1 = OFF_W2 + 2097152;       // (unused now)
static constexpr size_t OFF_F2 = OFF_F1 + 32768;         // 384*128 bf16 = 96 KB (swizzled [o][j])
static constexpr size_t OFF_H  = OFF_F2 + 98304;         // 64 tiles x 16KB bf16 (swizzled 64-row h tiles)

DEVI unsigned short f2bf(float f) {
  union { __hip_bfloat16 b; unsigned short u; } cv;
  cv.b = __float2bfloat16(f);
  return cv.u;
}
DEVI float bf2f(unsigned short u) {
  union { unsigned int i; float f; } cv;
  cv.i = ((unsigned int)u) << 16;
  return cv.f;
}

// Raw workgroup barrier: execution sync + LDS visibility (lgkmcnt), but does NOT
// drain vmcnt -> global prefetch loads stay in flight across it.
DEVI void bar_lds() {
  __builtin_amdgcn_sched_barrier(0);
  asm volatile("s_waitcnt lgkmcnt(0)" ::: "memory");
  __builtin_amdgcn_s_barrier();
  __builtin_amdgcn_sched_barrier(0);
}

// Read one MFMA fragment (8 contiguous bf16 along k) from a swizzled tile
// (LDS or global). Row stride 256B; 16B slot s stored at (s ^ (row&7)).
DEVI bf16x8 frag_ld(const unsigned char* base, int row, int kslot) {
  return *reinterpret_cast<const bf16x8*>(base + row * 256 + (((kslot ^ (row & 7)) << 4)));
}
// Unswizzled fragment read (global memory, 256B rows).
DEVI bf16x8 gfrag_ld(const unsigned char* base, int row, int kslot) {
  return *reinterpret_cast<const bf16x8*>(base + row * 256 + (kslot << 4));
}

// Stage an nrows x 128 fp32 tile (row stride in elems) into swizzled bf16 LDS.
DEVI void stage_f32_tile(const float* src, int row_stride, unsigned char* dst, int tid, int nrows) {
  for (int t = tid; t < nrows * 16; t += 256) {
    int row = t >> 4, s = t & 15;
    const float* p = src + (size_t)row * row_stride + s * 8;
    union { unsigned short u[8]; uint4 v; } pk;
#pragma unroll
    for (int j = 0; j < 8; ++j) pk.u[j] = f2bf(p[j]);
    *reinterpret_cast<uint4*>(dst + row * 256 + ((s ^ (row & 7)) << 4)) = pk.v;
  }
}

// ================ K1: prep (W1,W2,F2s,logits) || f1 (h = relu(emb@fc1^T+b1)) ================
// prep blocks 0..2071; f1 blocks 2072..2135. f1 reads emb+fc1w DIRECTLY from global
// (no dependency on prep), writes 64-row swizzled bf16 h tiles to ws+OFF_H.
__global__ __launch_bounds__(256) void prep_f1_kernel(const float* __restrict__ rw1,
                                                      const float* __restrict__ rw2,
                                                      const float* __restrict__ fc2w,
                                                      const float* __restrict__ slog,
                                                      const float* __restrict__ emb,
                                                      const float* __restrict__ fc1w,
                                                      const float* __restrict__ fc1b,
                                                      float* __restrict__ out,
                                                      unsigned char* __restrict__ ws) {
  __shared__ unsigned char sA[16384];  // f1: emb 64-row tile
  __shared__ unsigned char sB[32768];  // f1: fc1w tile

  const int bid = blockIdx.x;
  const int tid = threadIdx.x;
  if (bid < 2072) {
    const int T_W1 = 128 * 128 * 16;  // (n,s,c): W1t[n][c][h=s*8+j] = rw1[n][h][c]
    const int T_W2 = 128 * 64 * 16;   // (n,s,w): W2t[n][w][k=s*8+j] = rw2[n][k][w]
    const int T_F2 = 384 * 16;        // (o,s):   F2s[o][j] = fc2w[o][j]  (swizzled)
    int id = bid * 256 + tid;
    if (id < T_W1) {
      int c = id & 127, rest = id >> 7;
      int s = rest & 15, n = rest >> 4;
      const float* src = rw1 + (size_t)n * 16384 + (size_t)(s * 8) * 128 + c;
      union { unsigned short u[8]; uint4 v; } pk;
#pragma unroll
      for (int j = 0; j < 8; ++j) pk.u[j] = f2bf(src[(size_t)j * 128]);
      size_t dst = OFF_W1 + ((size_t)n * 128 + c) * 256 + (size_t)(s << 4);
      *reinterpret_cast<uint4*>(ws + dst) = pk.v;
      return;
    }
    id -= T_W1;
    if (id < T_W2) {
      int w = id & 63, rest = id >> 6;
      int s = rest & 15, n = rest >> 4;
      const float* src = rw2 + (size_t)n * 8192 + (size_t)(s * 8) * 64 + w;
      union { unsigned short u[8]; uint4 v; } pk;
#pragma unroll
      for (int j = 0; j < 8; ++j) pk.u[j] = f2bf(src[(size_t)j * 64]);
      size_t dst = OFF_W2 + ((size_t)n * 64 + w) * 256 + (size_t)(s << 4);
      *reinterpret_cast<uint4*>(ws + dst) = pk.v;
      return;
    }
    id -= T_W2;
    if (id < T_F2) {
      int s = id & 15, o = id >> 4;
      const float* src = fc2w + (size_t)o * 128 + s * 8;
      union { unsigned short u[8]; uint4 v; } pk;
#pragma unroll
      for (int j = 0; j < 8; ++j) pk.u[j] = f2bf(src[j]);
      *reinterpret_cast<uint4*>(ws + OFF_F2 + (size_t)o * 256 + ((s ^ (o & 7)) << 4)) = pk.v;
      return;
    }
    id -= T_F2;
    // logits passthrough: 2MB as uint4
    reinterpret_cast<uint4*>(out)[id] = reinterpret_cast<const uint4*>(slog)[id];
    return;
  }

  // ---- f1 path: 64 blocks x 64 b-rows ----
  const int bt = bid - 2072;
  const int b0 = bt * 64;
  stage_f32_tile(fc1w, 128, sB, tid, 128);
  stage_f32_tile(emb + (size_t)b0 * 128, 128, sA, tid, 64);
  __syncthreads();

  const int wave = tid >> 6, lane = tid & 63;
  const int wm = wave >> 1, wn = wave & 1;
  const int lr = lane & 15, lk = lane >> 4;

  f32x4 acc[2][4] = {};
#pragma unroll
  for (int kk = 0; kk < 4; ++kk) {
    const int slot = kk * 4 + lk;
    bf16x8 af[2], bfv[4];
#pragma unroll
    for (int m = 0; m < 2; ++m) af[m] = frag_ld(sA, wm * 32 + m * 16 + lr, slot);
#pragma unroll
    for (int q = 0; q < 4; ++q) bfv[q] = frag_ld(sB, wn * 64 + q * 16 + lr, slot);
#pragma unroll
    for (int m = 0; m < 2; ++m)
#pragma unroll
      for (int q = 0; q < 4; ++q)
        acc[m][q] = __builtin_amdgcn_mfma_f32_16x16x32_bf16(af[m], bfv[q], acc[m][q], 0, 0, 0);
  }

  unsigned char* tile = ws + OFF_H + (size_t)bt * 16384;
#pragma unroll
  for (int q = 0; q < 4; ++q) {
    int c = wn * 64 + q * 16 + lr;
    float bias = fc1b[c];
#pragma unroll
    for (int m = 0; m < 2; ++m) {
#pragma unroll
      for (int j = 0; j < 4; ++j) {
        int r = wm * 32 + m * 16 + lk * 4 + j;
        float v = acc[m][q][j] + bias;
        v = v > 0.f ? v : 0.f;
        *reinterpret_cast<unsigned short*>(tile + r * 256 + ((c * 2) ^ ((r & 7) << 4))) = f2bf(v);
      }
    }
  }
}

// ================ K2: recon (1024 blocks) || f2 (192 blocks) ================
// recon: per (n, 512-b range), 8x 64-row subtiles, v7 pipeline with register diet:
//   biases in LDS (768B), W2 frags re-read per iter from L2 (epi-phase issue),
//   wpref first in [C]-phase so fra/frb die before epi1. Target VGPR <= 170 ->
//   3 blocks/CU (LDS 49.9KB). Barriers are non-vmcnt-draining.
// f2: forecast = h @ fc2^T + b2, reading h tiles (global, L2-hot) + F2s from ws.
__global__ __launch_bounds__(256, 2) void recon_f2_kernel(const float* __restrict__ se,
                                                          const float* __restrict__ rb1,
                                                          const float* __restrict__ rb2,
                                                          const float* __restrict__ fc2b,
                                                          const unsigned char* __restrict__ ws,
                                                          float* __restrict__ out3,
                                                          float* __restrict__ out2) {
  __shared__ unsigned char smem[49920];

  const int bid = blockIdx.x;
  const int tid = threadIdx.x;
  const int wave = tid >> 6, lane = tid & 63;
  const int lr = lane & 15, lk = lane >> 4;

  if (bid >= 1024) {
    // ---- f2 path: 192 blocks (bt 0..63 x ch 0..2), 64 b-rows each ----
    const int fid = bid - 1024;
    const int bt = fid & 63, ch = fid >> 6;
    const int b0 = bt * 64;
    unsigned char* sB = smem;  // 32KB F2s chunk
    {
      const uint4* bp = reinterpret_cast<const uint4*>(ws + OFF_F2 + (size_t)ch * 32768);
      uint4* db = reinterpret_cast<uint4*>(sB);
      for (int c = tid; c < 2048; c += 256) db[c] = bp[c];
    }
    __syncthreads();

    const int wm = wave >> 1, wn = wave & 1;
    const unsigned char* htile = ws + OFF_H + (size_t)bt * 16384;

    f32x4 acc[2][4] = {};
#pragma unroll
    for (int kk = 0; kk < 4; ++kk) {
      const int slot = kk * 4 + lk;
      bf16x8 af[2], bfv[4];
#pragma unroll
      for (int m = 0; m < 2; ++m) af[m] = frag_ld(htile, wm * 32 + m * 16 + lr, slot);
#pragma unroll
      for (int q = 0; q < 4; ++q) bfv[q] = frag_ld(sB, wn * 64 + q * 16 + lr, slot);
#pragma unroll
      for (int m = 0; m < 2; ++m)
#pragma unroll
        for (int q = 0; q < 4; ++q)
          acc[m][q] = __builtin_amdgcn_mfma_f32_16x16x32_bf16(af[m], bfv[q], acc[m][q], 0, 0, 0);
    }

#pragma unroll
    for (int q = 0; q < 4; ++q) {
      int o = ch * 128 + wn * 64 + q * 16 + lr;
      float bias = fc2b[o];
#pragma unroll
      for (int m = 0; m < 2; ++m) {
#pragma unroll
        for (int j = 0; j < 4; ++j) {
          int r = wm * 32 + m * 16 + lk * 4 + j;
          out2[(size_t)(b0 + r) * 384 + o] = acc[m][q][j] + bias;
        }
      }
    }
    return;
  }

  // ---- recon path ----
  unsigned char* sSE0 = smem;
  unsigned char* sSE1 = smem + 16384;
  unsigned char* sHN = smem + 32768;
  float* sBIAS = reinterpret_cast<float*>(smem + 49152);  // [0..127] rb1, [128..191] rb2

  const int n = bid & 127;   // linear id % 8 == n % 8 -> same-n blocks share XCD
  const int btg = bid >> 7;  // 0..7
  const int b0 = btg * 512;

  const int wm = wave >> 1, wq = wave & 1;  // wm: out-row half, wq: b half (32 each)

  // W1 A-fragments (loop-invariant -> VGPR, 64 regs)
  const unsigned char* w1b = ws + OFF_W1 + (size_t)n * 32768;
  const unsigned char* w2b = ws + OFF_W2 + (size_t)n * 16384;
  bf16x8 w1f[4][4];
#pragma unroll
  for (int m = 0; m < 4; ++m)
#pragma unroll
    for (int kk = 0; kk < 4; ++kk)
      w1f[m][kk] = gfrag_ld(w1b, wm * 64 + m * 16 + lr, kk * 4 + lk);

  // biases -> LDS stub (no VGPR held across phases)
  if (tid < 192)
    sBIAS[tid] = (tid < 128) ? rb1[(size_t)n * 128 + tid] : rb2[(size_t)n * 64 + tid - 128];

  // stage SE subtile 0 directly
  stage_f32_tile(se + ((size_t)b0 * 128 + n) * 128, 128 * 128, sSE0, tid, 64);
  unsigned short* outus = reinterpret_cast<unsigned short*>(out3);

  float4 fra[4], frb[4];  // next-tile staging registers
  {  // prologue: issue loads for tile 1 (consumed at wpref of t=0)
    const float* sb = se + ((size_t)(b0 + 64) * 128 + n) * 128;
#pragma unroll
    for (int k = 0; k < 4; ++k) {
      int c = tid + k * 256;
      int row = c >> 4, s = c & 15;
      const float* p = sb + (size_t)row * 16384 + s * 8;
      fra[k] = *reinterpret_cast<const float4*>(p);
      frb[k] = *reinterpret_cast<const float4*>(p + 4);
    }
  }
  bar_lds();  // tile 0 + biases staged (no vmcnt drain: tile-1 loads stay in flight)

#pragma unroll 1
  for (int t = 0; t < 8; ++t) {
    unsigned char* bufc = (t & 1) ? sSE1 : sSE0;
    unsigned char* bufn = (t & 1) ? sSE0 : sSE1;

    // GEMM1': 128(h_out) x 64(b) x 128(k); wave owns 64 x 32
    f32x4 acc[4][2] = {};
#pragma unroll
    for (int kk = 0; kk < 4; ++kk) {
      const int slot = kk * 4 + lk;
      bf16x8 bv[2];
#pragma unroll
      for (int q = 0; q < 2; ++q) bv[q] = frag_ld(bufc, wq * 32 + q * 16 + lr, slot);
#pragma unroll
      for (int m = 0; m < 4; ++m)
#pragma unroll
        for (int q = 0; q < 2; ++q)
          acc[m][q] = __builtin_amdgcn_mfma_f32_16x16x32_bf16(w1f[m][kk], bv[q], acc[m][q], 0, 0, 0);
    }
    bar_lds();  // [C] all G1 reads of bufc done; prev G2's sHN reads done

    // write prefetched SE(t+1) FIRST (frees fra/frb before epi1 -> lower reg peak)
    if (t < 7) {
#pragma unroll
      for (int k = 0; k < 4; ++k) {
        int c = tid + k * 256;
        int row = c >> 4, s = c & 15;
        union { unsigned short u[8]; uint4 v; } pk;
#pragma unroll
        for (int j = 0; j < 4; ++j) pk.u[j] = f2bf(fra[k][j]);
#pragma unroll
        for (int j = 0; j < 4; ++j) pk.u[4 + j] = f2bf(frb[k][j]);
        *reinterpret_cast<uint4*>(bufn + row * 256 + ((s ^ (row & 7)) << 4)) = pk.v;
      }
    }
    // issue loads for tile t+2 (consumed at wpref(t+1); crosses two non-draining barriers)
    if (t < 6) {
      const float* sb = se + ((size_t)(b0 + (t + 2) * 64) * 128 + n) * 128;
#pragma unroll
      for (int k = 0; k < 4; ++k) {
        int c = tid + k * 256;
        int row = c >> 4, s = c & 15;
        const float* p = sb + (size_t)row * 16384 + s * 8;
        fra[k] = *reinterpret_cast<const float4*>(p);
        frb[k] = *reinterpret_cast<const float4*>(p + 4);
      }
    }
    // W2 A-fragments: re-read from L2 each iter (same addr -> hot); used after [F]
    bf16x8 w2f[2][4];
#pragma unroll
    for (int m = 0; m < 2; ++m)
#pragma unroll
      for (int kk = 0; kk < 4; ++kk)
        w2f[m][kk] = gfrag_ld(w2b, wm * 32 + m * 16 + lr, kk * 4 + lk);

    // epilogue1: hn[b][k] = relu(C1t[k][b] + rb1[k]) -> bf16 into sHN (bias from LDS)
#pragma unroll
    for (int m = 0; m < 4; ++m) {
      const int k0 = wm * 64 + m * 16 + lk * 4;
      const int s16 = k0 >> 3, half = (k0 >> 2) & 1;
      union { float4 v; float f[4]; } b1;
      b1.v = *reinterpret_cast<const float4*>(sBIAS + k0);
#pragma unroll
      for (int q = 0; q < 2; ++q) {
        const int b = wq * 32 + q * 16 + lr;
        union { unsigned short u[4]; uint2 v; } pk;
#pragma unroll
        for (int j = 0; j < 4; ++j) {
          float v = acc[m][q][j] + b1.f[j];
          v = v > 0.f ? v : 0.f;
          pk.u[j] = f2bf(v);
        }
        *reinterpret_cast<uint2*>(sHN + b * 256 + ((s16 ^ (b & 7)) << 4) + half * 8) = pk.v;
      }
    }
    bar_lds();  // [F] sHN + bufn ready

    // GEMM2': 64(w) x 64(b) x 128(k); wave owns 32 x 32
    f32x4 acc2[2][2] = {};
#pragma unroll
    for (int kk = 0; kk < 4; ++kk) {
      const int slot = kk * 4 + lk;
      bf16x8 bv[2];
#pragma unroll
      for (int q = 0; q < 2; ++q) bv[q] = frag_ld(sHN, wq * 32 + q * 16 + lr, slot);
#pragma unroll
      for (int m = 0; m < 2; ++m)
#pragma unroll
        for (int q = 0; q < 2; ++q)
          acc2[m][q] = __builtin_amdgcn_mfma_f32_16x16x32_bf16(w2f[m][kk], bv[q], acc2[m][q], 0, 0, 0);
    }

    // epilogue2: tmp[b][n][w] bf16 at float-offset 4096 of b's out3 slot (bias from LDS)
    const int bt0 = b0 + t * 64;
#pragma unroll
    for (int m = 0; m < 2; ++m) {
      const int w0 = wm * 32 + m * 16 + lk * 4;
      union { float4 v; float f[4]; } b2;
      b2.v = *reinterpret_cast<const float4*>(sBIAS + 128 + w0);
#pragma unroll
      for (int q = 0; q < 2; ++q) {
        const int b = bt0 + wq * 32 + q * 16 + lr;
        union { unsigned short u[4]; uint2 v; } pk;
#pragma unroll
        for (int j = 0; j < 4; ++j) pk.u[j] = f2bf(acc2[m][q][j] + b2.f[j]);
        *reinterpret_cast<uint2*>(outus + (size_t)b * 16384 + 8192 + n * 64 + w0) = pk.v;
      }
    }
    // no closing barrier: G2(t) r:sHN vs epi1(t+1) w:sHN separated by [C](t+1);
    // wpref(t) w:bufn vs G1(t+1) r:bufn separated by [F](t).
  }
}

// ================ K3: transpose tmp bf16 [b][n][w] -> out3 fp32 [b][w][n] ================
__global__ __launch_bounds__(256) void transpose_kernel(float* __restrict__ out3) {
  const int b = blockIdx.x, wave = threadIdx.x >> 6, lane = threadIdx.x & 63;
  const unsigned short* t = reinterpret_cast<const unsigned short*>(out3) + (size_t)b * 16384 + 8192;
  float* dst = out3 + (size_t)b * 8192;
  uint4 r[2][2];
#pragma unroll
  for (int half = 0; half < 2; ++half) {
    const int g = half * 4 + wave;
    r[half][0] = *reinterpret_cast<const uint4*>(t + lane * 64 + g * 8);
    r[half][1] = *reinterpret_cast<const uint4*>(t + (size_t)(lane + 64) * 64 + g * 8);
  }
  __syncthreads();  // all reads done before dst writes clobber the tmp region
#pragma unroll
  for (int half = 0; half < 2; ++half) {
    const int g = half * 4 + wave;
    union { uint4 v; unsigned short u[8]; } p0, p1;
    p0.v = r[half][0];
    p1.v = r[half][1];
#pragma unroll
    for (int j = 0; j < 8; ++j) {
      dst[(g * 8 + j) * 128 + lane] = bf2f(p0.u[j]);
      dst[(g * 8 + j) * 128 + lane + 64] = bf2f(p1.u[j]);
    }
  }
}

extern "C" void kernel_launch(void* const* d_in, const int* in_sizes, int n_in,
                              void* d_out, int out_size, void* d_ws, size_t ws_size,
                              hipStream_t stream) {
  const float* emb  = (const float*)d_in[0];
  const float* se   = (const float*)d_in[1];
  const float* slog = (const float*)d_in[2];
  const float* fc1w = (const float*)d_in[3];
  const float* fc1b = (const float*)d_in[4];
  const float* fc2w = (const float*)d_in[5];
  const float* fc2b = (const float*)d_in[6];
  const float* rw1  = (const float*)d_in[7];
  const float* rb1  = (const float*)d_in[8];
  const float* rw2  = (const float*)d_in[9];
  const float* rb2  = (const float*)d_in[10];
  float* out = (float*)d_out;
  unsigned char* ws = (unsigned char*)d_ws;

  float* out2 = out + (size_t)B_SZ * N_SZ;
  float* out3 = out2 + (size_t)B_SZ * 384;

  // K1: weight prep + logits copy || forecast stage 1
  prep_f1_kernel<<<2136, 256, 0, stream>>>(rw1, rw2, fc2w, slog, emb, fc1w, fc1b, out, ws);

  // K2: reconstruction (dominant) || forecast stage 2
  recon_f2_kernel<<<1216, 256, 0, stream>>>(se, rb1, rb2, fc2b, ws, out3, out2);

  // K3: transpose to final [b][w][n] fp32
  transpose_kernel<<<4096, 256, 0, stream>>>(out3);
}